// Round 1
// baseline (255.625 us; speedup 1.0000x reference)
//
#include <hip/hip_runtime.h>
#include <cstdint>
#include <cstddef>

// Qwen3AttentionModified: B=1 S=2048 D=2048 H=16 KVH=8 HD=128
// pipeline: cast hs->bf16; transpose+cast weights; QKV GEMM (bf16 MFMA, fp32 out);
// norm*denom+RoPE -> Q,K bf16 [h][s][d]; V -> bf16 transposed [kvh][d][s];
// attention (no softmax; elementwise ((s*scale+shift)/rd)^8, causal tiles only);
// O GEMM -> fp32 d_out.

namespace {
constexpr int kS = 2048;
constexpr int kD = 2048;
constexpr int kH = 16;
constexpr int kKVH = 8;
constexpr int kHD = 128;
constexpr float kScale = 0.08838834764831845f;  // 128^-0.5
}  // namespace

using f32x4 = __attribute__((ext_vector_type(4))) float;
using bfrag = __attribute__((ext_vector_type(8))) short;   // 8 x bf16 (4 VGPR)
using float4v = __attribute__((ext_vector_type(4))) float;
using short4v = __attribute__((ext_vector_type(4))) short;

__device__ __forceinline__ unsigned short f2b(float f) {
  union { float f; unsigned u; } x; x.f = f;
  unsigned r = x.u + 0x7FFFu + ((x.u >> 16) & 1u);  // RNE
  return (unsigned short)(r >> 16);
}

__device__ __forceinline__ void gload_lds16(const void* g, void* l) {
  __builtin_amdgcn_global_load_lds(
      (const __attribute__((address_space(1))) unsigned*)g,
      (__attribute__((address_space(3))) unsigned*)l, 16, 0, 0);
}

// ---------------- cast fp32 -> bf16 (contiguous, vectorized) ----------------
__global__ __launch_bounds__(256) void qwen_cast_bf16(const float* __restrict__ in,
                                                      unsigned short* __restrict__ out,
                                                      int n4) {
  int i = blockIdx.x * 256 + threadIdx.x;
  if (i >= n4) return;
  float4v v = *(const float4v*)(in + (size_t)i * 4);
  short4v o;
  o[0] = (short)f2b(v[0]); o[1] = (short)f2b(v[1]);
  o[2] = (short)f2b(v[2]); o[3] = (short)f2b(v[3]);
  *(short4v*)(out + (size_t)i * 4) = o;
}

// ------------- transpose + cast: in fp32 [R][C] -> out bf16 [C][ldo] -------------
__global__ __launch_bounds__(256) void qwen_tw(const float* __restrict__ in, int R, int C,
                                               unsigned short* __restrict__ out, int ldo) {
  __shared__ float t[64][65];  // +1 pad: conflict-free column reads
  int c0 = blockIdx.x * 64, r0 = blockIdx.y * 64;
  int tr = threadIdx.x >> 6, tc = threadIdx.x & 63;
#pragma unroll
  for (int p = 0; p < 16; ++p) {
    int i = p * 4 + tr;
    t[i][tc] = in[(size_t)(r0 + i) * C + c0 + tc];
  }
  __syncthreads();
#pragma unroll
  for (int p = 0; p < 16; ++p) {
    int i = p * 4 + tr;
    out[(size_t)(c0 + i) * ldo + r0 + tc] = f2b(t[tc][i]);
  }
}

// ------------- GEMM: C[M][N] fp32 = A[M][K] bf16 @ Bt[N][K] bf16 (m97 structure) -------------
__global__ __launch_bounds__(256) void qwen_gemm_bt(const unsigned short* __restrict__ A,
                                                    const unsigned short* __restrict__ Bt,
                                                    float* __restrict__ C,
                                                    int M, int N, int K) {
  __shared__ unsigned short As[128 * 32];
  __shared__ unsigned short Bs[128 * 32];
  const int tid = threadIdx.x;
  const int lane = tid & 63;
  const int w = tid >> 6;
  const int wr = w >> 1, wc = w & 1;  // 2x2 wave grid, 64x64 out per wave
  const int row0 = blockIdx.x * 128, col0 = blockIdx.y * 128;
  f32x4 acc[4][4] = {};
  const int koff = (lane >> 4) << 3;
  const int rA = wr * 64 + (lane & 15);
  const int rB = wc * 64 + (lane & 15);
  for (int kt = 0; kt < K; kt += 32) {
#pragma unroll
    for (int c = 0; c < 2; ++c) {
      int off = w * 2048 + c * 1024;  // byte offset into 8KB tile
      int e = (off >> 1) + lane * 8;  // element index; lane lands at off + lane*16
      int r = e >> 5, cc = e & 31;
      gload_lds16(A + (size_t)(row0 + r) * K + kt + cc, (char*)As + off);
      gload_lds16(Bt + (size_t)(col0 + r) * K + kt + cc, (char*)Bs + off);
    }
    __syncthreads();  // drains vmcnt before frag reads
    bfrag aF[4], bF[4];
#pragma unroll
    for (int m = 0; m < 4; ++m) aF[m] = *(const bfrag*)(As + (rA + m * 16) * 32 + koff);
#pragma unroll
    for (int n = 0; n < 4; ++n) bF[n] = *(const bfrag*)(Bs + (rB + n * 16) * 32 + koff);
#pragma unroll
    for (int m = 0; m < 4; ++m)
#pragma unroll
      for (int n = 0; n < 4; ++n)
        acc[m][n] = __builtin_amdgcn_mfma_f32_16x16x32_bf16(aF[m], bF[n], acc[m][n], 0, 0, 0);
    __syncthreads();  // before next-tile overwrite
  }
  const int cr = (lane >> 4) << 2;
  const int cc2 = lane & 15;
#pragma unroll
  for (int m = 0; m < 4; ++m)
#pragma unroll
    for (int n = 0; n < 4; ++n) {
      int r = row0 + wr * 64 + m * 16 + cr;
      int c = col0 + wc * 64 + n * 16 + cc2;
#pragma unroll
      for (int j = 0; j < 4; ++j) C[(size_t)(r + j) * N + c] = acc[m][n][j];
    }
}

// ------------- epilogue: denom*norm + RoPE; Cqkv fp32 [S][4096] -> Qb/Kb bf16 [h][s][d] -------------
__global__ __launch_bounds__(256) void qwen_rope_qk(const float* __restrict__ Cqkv,
                                                    const float* __restrict__ cosb,
                                                    const float* __restrict__ sinb,
                                                    const float* __restrict__ qnw,
                                                    const float* __restrict__ knw,
                                                    const float* __restrict__ qden,
                                                    const float* __restrict__ kden,
                                                    unsigned short* __restrict__ Qb,
                                                    unsigned short* __restrict__ Kb) {
  int s = blockIdx.x;
  int t = threadIdx.x;
  const float* row = Cqkv + (size_t)s * 4096;
  const float* cs = cosb + (size_t)s * kHD;
  const float* sn = sinb + (size_t)s * kHD;
#pragma unroll
  for (int rep = 0; rep < 8; ++rep) {  // 2048 Q elems
    int idx = rep * 256 + t;
    int h = idx >> 7, d = idx & 127;
    float dn = qden[s * kH + h];
    float v = row[idx] * dn * qnw[d];
    float pv = row[(h << 7) + (d ^ 64)] * dn * qnw[d ^ 64];
    float rot = (d < 64) ? -pv : pv;  // rotate_half
    Qb[((size_t)h * kS + s) * kHD + d] = f2b(v * cs[d] + rot * sn[d]);
  }
#pragma unroll
  for (int rep = 0; rep < 4; ++rep) {  // 1024 K elems
    int idx = rep * 256 + t;
    int h = idx >> 7, d = idx & 127;
    float dn = kden[s * kKVH + h];
    float v = row[2048 + idx] * dn * knw[d];
    float pv = row[2048 + (h << 7) + (d ^ 64)] * dn * knw[d ^ 64];
    float rot = (d < 64) ? -pv : pv;
    Kb[((size_t)h * kS + s) * kHD + d] = f2b(v * cs[d] + rot * sn[d]);
  }
}

// ------------- V: Cqkv fp32 cols [3072..4096) -> Vt bf16 [kvh][d][s] (tiled transpose) -------------
__global__ __launch_bounds__(256) void qwen_vtr(const float* __restrict__ Cqkv,
                                                unsigned short* __restrict__ Vt) {
  __shared__ float t[64][65];
  int kvh = blockIdx.x, st = blockIdx.y, dt = blockIdx.z;
  int s0 = st * 64, d0 = dt * 64;
  int tr = threadIdx.x >> 6, tc = threadIdx.x & 63;
#pragma unroll
  for (int p = 0; p < 16; ++p) {
    int i = p * 4 + tr;
    t[i][tc] = Cqkv[(size_t)(s0 + i) * 4096 + 3072 + (kvh << 7) + d0 + tc];
  }
  __syncthreads();
#pragma unroll
  for (int p = 0; p < 16; ++p) {
    int i = p * 4 + tr;
    Vt[(size_t)((kvh << 7) + d0 + i) * kS + s0 + tc] = f2b(t[tc][i]);
  }
}

// ------------- attention: per (q-tile 128, head); causal tiles only -------------
__global__ __launch_bounds__(256, 1) void qwen_attn(const unsigned short* __restrict__ Qb,
                                                    const unsigned short* __restrict__ Kb,
                                                    const unsigned short* __restrict__ Vtb,
                                                    const float* __restrict__ rd,
                                                    unsigned short* __restrict__ AO) {
  __shared__ unsigned short Ks[128 * 128];  // [key][d]  swizzled
  __shared__ unsigned short Vs[128 * 128];  // [d][key]  swizzled
  __shared__ unsigned short Ps[128 * 128];  // [q][key]  swizzled
  const int qt = blockIdx.x, h = blockIdx.y;
  const int kvh = h >> 1;  // GQA groups=2
  const int tid = threadIdx.x, lane = tid & 63, w = tid >> 6;
  const int wr = w >> 1, wc = w & 1;
  const int koff = (lane >> 4) << 3;
  const int l15 = lane & 15;

  // Q fragments in registers (16 x b128 loads); row=lane&15, k contiguous 8
  bfrag qF[4][4];
  {
    const unsigned short* Qg = Qb + ((size_t)h * kS + qt * 128) * kHD;
#pragma unroll
    for (int m = 0; m < 4; ++m)
#pragma unroll
      for (int kc = 0; kc < 4; ++kc)
        qF[m][kc] = *(const bfrag*)(Qg + (size_t)(wr * 64 + m * 16 + l15) * kHD + kc * 32 + koff);
  }
  // rd is per (head, q-row): precompute scale/shift per accumulator row
  float ascl[4][4], bshift[4][4];
  {
    const float* rdp = rd + (size_t)h * kS + qt * 128 + wr * 64 + ((lane >> 4) << 2);
#pragma unroll
    for (int m = 0; m < 4; ++m)
#pragma unroll
      for (int j = 0; j < 4; ++j) {
        float inv = 1.0f / rdp[m * 16 + j];
        ascl[m][j] = kScale * inv;
        bshift[m][j] = 7.0f * inv;  // (mask 0) + C_SHIFT, divided by rd
      }
  }
  f32x4 outa[4][4] = {};
  const unsigned short* Kg0 = Kb + (size_t)kvh * kS * kHD;
  const unsigned short* Vg0 = Vtb + (size_t)kvh * kHD * kS;

  for (int kt = 0; kt <= qt; ++kt) {
    // stage K tile [key][d], XOR-swizzled (rule #21: same swizzle write+read)
    {
      const unsigned short* Kg = Kg0 + (size_t)kt * 128 * kHD;
#pragma unroll
      for (int it = 0; it < 8; ++it) {
        int e = (it * 256 + tid) * 8;
        int key = e >> 7, dc = e & 127;
        bfrag v = *(const bfrag*)(Kg + (size_t)key * kHD + dc);
        int ba = key * 256 + ((dc * 2) ^ ((key & 7) << 4));
        *(bfrag*)((char*)Ks + ba) = v;
      }
    }
    __syncthreads();
    // QK^T: sc[q][key]
    f32x4 sc[4][4] = {};
#pragma unroll
    for (int n = 0; n < 4; ++n) {
      int key = wc * 64 + n * 16 + l15;
      bfrag kF[4];
#pragma unroll
      for (int kc = 0; kc < 4; ++kc) {
        int kb = kc * 32 + koff;
        kF[kc] = *(const bfrag*)((char*)Ks + key * 256 + ((kb * 2) ^ ((key & 7) << 4)));
      }
#pragma unroll
      for (int m = 0; m < 4; ++m)
#pragma unroll
        for (int kc = 0; kc < 4; ++kc)
          sc[m][n] = __builtin_amdgcn_mfma_f32_16x16x32_bf16(qF[m][kc], kF[kc], sc[m][n], 0, 0, 0);
    }
    // elementwise ((s*scale + mask + 7)/rd)^8 -> Ps bf16 (swizzled)
    const bool diag = (kt == qt);
#pragma unroll
    for (int m = 0; m < 4; ++m)
#pragma unroll
      for (int j = 0; j < 4; ++j) {
        int rloc = wr * 64 + m * 16 + ((lane >> 4) << 2) + j;
        float a = ascl[m][j], b = bshift[m][j];
#pragma unroll
        for (int n = 0; n < 4; ++n) {
          int c = wc * 64 + n * 16 + l15;
          bool ok = !diag || (c <= rloc);  // masked: -7+7=0 shift
          float y = sc[m][n][j] * a + (ok ? b : 0.0f);
          float y2 = y * y, y4 = y2 * y2;
          int ba = rloc * 256 + ((c * 2) ^ ((rloc & 7) << 4));
          *(unsigned short*)((char*)Ps + ba) = f2b(y4 * y4);
        }
      }
    // stage V tile [d][key], swizzled
    {
      const unsigned short* Vg = Vg0 + kt * 128;
#pragma unroll
      for (int it = 0; it < 8; ++it) {
        int e = (it * 256 + tid) * 8;
        int dd = e >> 7, key0 = e & 127;
        bfrag v = *(const bfrag*)(Vg + (size_t)dd * kS + key0);
        int ba = dd * 256 + ((key0 * 2) ^ ((dd & 7) << 4));
        *(bfrag*)((char*)Vs + ba) = v;
      }
    }
    __syncthreads();  // fences Ps writes (cross-wave reads) + Vs staging
    // PV: out[q][hd] += P[q][key] @ V[key][hd]
#pragma unroll
    for (int kc = 0; kc < 4; ++kc) {
      int kb = kc * 32 + koff;
      bfrag pF[4], vF[4];
#pragma unroll
      for (int m = 0; m < 4; ++m) {
        int rp = wr * 64 + m * 16 + l15;
        pF[m] = *(const bfrag*)((char*)Ps + rp * 256 + ((kb * 2) ^ ((rp & 7) << 4)));
      }
#pragma unroll
      for (int n = 0; n < 4; ++n) {
        int rv = wc * 64 + n * 16 + l15;
        vF[n] = *(const bfrag*)((char*)Vs + rv * 256 + ((kb * 2) ^ ((rv & 7) << 4)));
      }
#pragma unroll
      for (int m = 0; m < 4; ++m)
#pragma unroll
        for (int n = 0; n < 4; ++n)
          outa[m][n] = __builtin_amdgcn_mfma_f32_16x16x32_bf16(pF[m], vF[n], outa[m][n], 0, 0, 0);
    }
    __syncthreads();  // before next kt overwrites Ks/Vs/Ps
  }
  // AO bf16 [s][h*128+d]
  {
    const int cr = (lane >> 4) << 2;
#pragma unroll
    for (int m = 0; m < 4; ++m)
#pragma unroll
      for (int n = 0; n < 4; ++n) {
        int r = qt * 128 + wr * 64 + m * 16 + cr;
        int c = (h << 7) + wc * 64 + n * 16 + l15;
#pragma unroll
        for (int j = 0; j < 4; ++j)
          AO[(size_t)(r + j) * kD + c] = f2b(outa[m][n][j]);
      }
  }
}

extern "C" void kernel_launch(void* const* d_in, const int* in_sizes, int n_in,
                              void* d_out, int out_size, void* d_ws, size_t ws_size,
                              hipStream_t stream) {
  (void)in_sizes; (void)n_in; (void)out_size; (void)ws_size;
  const float* hidden = (const float*)d_in[0];
  const float* cosb   = (const float*)d_in[1];
  const float* sinb   = (const float*)d_in[2];
  const float* qw     = (const float*)d_in[3];
  const float* kw     = (const float*)d_in[4];
  const float* vw     = (const float*)d_in[5];
  const float* ow     = (const float*)d_in[6];
  const float* qnw    = (const float*)d_in[7];
  const float* knw    = (const float*)d_in[8];
  const float* qden   = (const float*)d_in[9];
  const float* kden   = (const float*)d_in[10];
  const float* rd     = (const float*)d_in[11];
  // d_in[12] attention_mask: reproduced inline (causal 0/-7), unused.
  float* out = (float*)d_out;

  char* ws = (char*)d_ws;
  size_t off = 0;
  auto alloc = [&](size_t bytes) { char* p = ws + off; off += bytes; return p; };
  unsigned short* hsb = (unsigned short*)alloc((size_t)2048 * 2048 * 2);  //  8 MB
  unsigned short* Wt  = (unsigned short*)alloc((size_t)4096 * 2048 * 2);  // 16 MB [q;k;v]^T
  unsigned short* Ot  = (unsigned short*)alloc((size_t)2048 * 2048 * 2);  //  8 MB
  float*          Cqkv= (float*)alloc((size_t)2048 * 4096 * 4);           // 32 MB
  unsigned short* Qb  = (unsigned short*)alloc((size_t)16 * 2048 * 128 * 2); // 8 MB
  unsigned short* Kb  = (unsigned short*)alloc((size_t)8 * 2048 * 128 * 2);  // 4 MB
  unsigned short* Vtb = (unsigned short*)alloc((size_t)8 * 128 * 2048 * 2);  // 4 MB
  unsigned short* AO  = (unsigned short*)alloc((size_t)2048 * 2048 * 2);     // 8 MB

  qwen_cast_bf16<<<4096, 256, 0, stream>>>(hidden, hsb, 2048 * 2048 / 4);
  qwen_tw<<<dim3(32, 32), 256, 0, stream>>>(qw, 2048, 2048, Wt, 2048);
  qwen_tw<<<dim3(16, 32), 256, 0, stream>>>(kw, 2048, 1024, Wt + (size_t)2048 * 2048, 2048);
  qwen_tw<<<dim3(16, 32), 256, 0, stream>>>(vw, 2048, 1024, Wt + (size_t)3072 * 2048, 2048);
  qwen_tw<<<dim3(32, 32), 256, 0, stream>>>(ow, 2048, 2048, Ot, 2048);
  qwen_gemm_bt<<<dim3(16, 32), 256, 0, stream>>>(hsb, Wt, Cqkv, 2048, 4096, 2048);
  qwen_rope_qk<<<2048, 256, 0, stream>>>(Cqkv, cosb, sinb, qnw, knw, qden, kden, Qb, Kb);
  qwen_vtr<<<dim3(8, 32, 2), 256, 0, stream>>>(Cqkv, Vtb);
  qwen_attn<<<dim3(16, 16), 256, 0, stream>>>(Qb, Kb, Vtb, rd, AO);
  qwen_gemm_bt<<<dim3(16, 16), 256, 0, stream>>>(AO, Ot, out, 2048, 2048, 2048);
}